// Round 2
// baseline (3801.262 us; speedup 1.0000x reference)
//
#include <hip/hip_runtime.h>
#include <cmath>
#include <climits>

#define N_ 2048
#define T_ 4096
#define MAXSP 256
#define CHUNK 256
#define NCHUNK (T_ / CHUNK)   // 16

// ---------------- workspace layout (d_ws) ----------------
#define WS_EIDX_OFF   0
#define WS_CNT_OFF    (T_ * 4)
#define WS_SNAP_OFF   (T_ * 4 + NCHUNK * 4)

typedef float f2 __attribute__((ext_vector_type(2)));

__device__ __forceinline__ int imin(int a, int b) { return a < b ? a : b; }

// Raw workgroup barrier with LDS visibility only (no vmcnt drain):
// global prefetches (ic, u_re, w-row) stay in flight across it.
__device__ __forceinline__ void lds_barrier() {
    asm volatile("s_waitcnt lgkmcnt(0)\n\ts_barrier" ::: "memory");
}

// Fill tevents/yevents with +inf, event_types with 0.
__global__ void snn_init_tail(float* __restrict__ out) {
    const size_t base    = (size_t)T_ * N_ * 3;
    const size_t inf_cnt = (size_t)MAXSP + (size_t)MAXSP * N_ * 3;
    const size_t tot     = inf_cnt + (size_t)MAXSP * N_;
    size_t idx = (size_t)blockIdx.x * blockDim.x + threadIdx.x;
    if (idx < tot) {
        out[base + idx] = (idx < inf_cnt) ? __builtin_inff() : 0.0f;
    }
}

// ---------------- Kernel A: sequential scan (1 WG, reduction-ahead) ------
// Pipeline invariant at top of iter k:
//   vA,sA   = post-transition state after step k-1
//   iRaw    = decayed i after step k-1, WITHOUT the event-(k-1) w row
//   evP,w2  = pending event at k-1 + its w row (load issued at top of k-1)
//   m0c,m1c,s1c = mask/intensity for step k (computed at iter k-1)
//   red[k&3] = fully-reduced candidate for step k (atomics drained by the
//              barrier of iter k-1)  -> readable at the TOP of iter k.
extern "C" __global__ void __launch_bounds__(1024)
snn_scan(const float* __restrict__ w,   const float* __restrict__ mu,
         const float* __restrict__ v0,  const float* __restrict__ i0,
         const float* __restrict__ ic,  const float* __restrict__ u_init,
         const float* __restrict__ u_re, float* __restrict__ out,
         int* __restrict__ ws_eidx, int* __restrict__ ws_cnt,
         float* __restrict__ ws_snap)
{
#pragma clang fp contract(off)
    const int tid = threadIdx.x;
    const int n0  = tid * 2;             // two adjacent neurons -> f2 ops
    const int wv  = tid >> 6, lane = tid & 63;
    const float dt = 1.0f / 4096.0f;     // exact: 2^-12
    const float mu1 = mu[0], mu2 = mu[1];

    float* tev = out + (size_t)T_ * N_ * 3;
    float* nsp = tev + MAXSP + (size_t)MAXSP * N_ * 3 + (size_t)MAXSP * N_;

    f2 vA, sA, iRaw;
    vA   = *(const f2*)(v0 + n0);
    iRaw = *(const f2*)(i0 + n0);
    { f2 a = *(const f2*)(u_init + n0);
      sA.x = logf(a.x) - 0.01f; sA.y = logf(a.y) - 0.01f; }  // one-time precise

    bool evP = false;
    f2 w2;   w2.x = 0.0f; w2.y = 0.0f;
    f2 wNew; wNew.x = 0.0f; wNew.y = 0.0f;

    // Slot lifecycle (mod 4): atomics at iter s-1 (pre-barrier) -> read at
    // top of iter s -> reset by tid0 at iter s+1 (post-barrier) -> next
    // atomics at iter s+3.  Every conflicting pair is separated by >=1
    // lds_barrier (lgkmcnt(0) drain + s_barrier).
    __shared__ int red[4];
    if (tid == 0) { red[0] = INT_MAX; red[1] = INT_MAX;
                    red[2] = INT_MAX; red[3] = INT_MAX; }

    // 3-deep prefetch pipeline for ic and u_re
    const float* icp = ic + n0;
    const float* up  = u_re + n0;
    f2 icA = *(const f2*)(icp);
    f2 icB = *(const f2*)(icp + N_);
    f2 icC = *(const f2*)(icp + 2 * N_);
    f2 uA  = *(const f2*)(up);
    f2 uB  = *(const f2*)(up + N_);
    f2 uC  = *(const f2*)(up + 2 * N_);
    icp += 3 * N_; up += 3 * N_;

    lds_barrier();   // red[] init visible before prologue atomics

    // ---- prologue: mask/candidate for step 0 -> slot 0
    f2 s1c; bool m0c, m1c;
    {
        f2 sp;
        bool slow = (fminf(vA.x, vA.y) < 16.0f);
        if (__ballot(slow)) {
            sp.x = fmaxf(vA.x, 0.0f) + __logf(1.0f + __expf(-fabsf(vA.x)));
            sp.y = fmaxf(vA.y, 0.0f) + __logf(1.0f + __expf(-fabsf(vA.y)));
        } else {
            sp = vA;
        }
        s1c = sA + dt * sp;
        m0c = (s1c.x >= 0.0f); m1c = (s1c.y >= 0.0f);
        unsigned long long b0 = __ballot(m0c);
        unsigned long long b1 = __ballot(m1c);
        if (b0 | b1) {
            int c0 = b0 ? (((int)__ffsll((long long)b0) - 1) << 1) : INT_MAX;
            int c1 = b1 ? ((((int)__ffsll((long long)b1) - 1) << 1) | 1) : INT_MAX;
            int cand = (wv << 7) + imin(c0, c1);
            if (lane == 0) atomicMin(&red[0], cand);
        }
    }
    lds_barrier();   // drain step-0 candidate atomics

    int cnt = 0;
#pragma unroll 4
    for (int k = 0; k < T_; ++k) {
        // [1] step-k event index is ALREADY reduced: read + scalarize now,
        //     issue the w-row load immediately (consumed at [3] of iter k+1
        //     -> a full iteration of latency slack).
        int eidx = red[k & 3];
        eidx = __builtin_amdgcn_readfirstlane(eidx);
        const bool evK = (eidx != INT_MAX);
        if (evK) wNew = *(const f2*)(w + (size_t)eidx * N_ + n0);

        // [3] finalize i_{k-1}: w row was issued at top of iter k-1
        f2 ip = iRaw;
        if (evP) ip += w2;

        // [4] chunk snapshot: state after step k-1 (= chunk-start state)
        if ((k & (CHUNK - 1)) == 0) {
            const int c = k >> 8;
            float* spn = ws_snap + (size_t)c * 3 * N_;
            *(f2*)(spn + n0)          = vA;
            *(f2*)(spn + N_ + n0)     = ip;
            *(f2*)(spn + 2 * N_ + n0) = sA;
            if (tid == 0) ws_cnt[c] = cnt;
        }

        // [5] Euler for step k — reference op order, no FMA contraction
        f2 v1 = vA + dt * (mu1 * ((ip + icA) - vA));
        iRaw  = ip + dt * ((-mu2) * ip);

        // [6] transitions for step k (masks precomputed at iter k-1)
        vA.x = m0c ? (v1.x - 1.0f) : v1.x;
        vA.y = m1c ? (v1.y - 1.0f) : v1.y;
        if (evK) {
            sA.x = m0c ? (__logf(uA.x) - 0.01f) : s1c.x;
            sA.y = m1c ? (__logf(uA.y) - 0.01f) : s1c.y;
            if (tid == 0) {
                ws_eidx[k] = eidx;
                if (cnt < MAXSP) tev[cnt] = (float)(k + 1) * dt;
            }
            if (cnt < MAXSP) cnt++;
        } else {
            sA = s1c;
            if (tid == 0) ws_eidx[k] = -1;
        }
        evP = evK;
        w2  = wNew;

        // [7] mask/candidate for step k+1 from post-step-k state (local:
        //     the event-(k) w row only reaches the mask at step k+2).
        if (k + 1 < T_) {
            f2 sp;
            bool slow = (fminf(vA.x, vA.y) < 16.0f);
            if (__ballot(slow)) {
                sp.x = fmaxf(vA.x, 0.0f) + __logf(1.0f + __expf(-fabsf(vA.x)));
                sp.y = fmaxf(vA.y, 0.0f) + __logf(1.0f + __expf(-fabsf(vA.y)));
            } else {
                sp = vA;
            }
            s1c = sA + dt * sp;
            m0c = (s1c.x >= 0.0f); m1c = (s1c.y >= 0.0f);
            unsigned long long b0 = __ballot(m0c);
            unsigned long long b1 = __ballot(m1c);
            if (b0 | b1) {
                int c0 = b0 ? (((int)__ffsll((long long)b0) - 1) << 1) : INT_MAX;
                int c1 = b1 ? ((((int)__ffsll((long long)b1) - 1) << 1) | 1) : INT_MAX;
                int cand = (wv << 7) + imin(c0, c1);
                if (lane == 0) atomicMin(&red[(k + 1) & 3], cand);
            }
        }

        // [8] barrier drains the slot-(k+1) atomics; slot (k+1) becomes
        //     readable at the top of iter k+1 with zero dependent work here.
        lds_barrier();
        if (tid == 0) red[(k + 3) & 3] = INT_MAX;   // deferred, race-free reset

        // [9] advance 3-deep prefetch
        icA = icB; icB = icC; uA = uB; uB = uC;
        if (k + 3 < T_) {
            icC = *(const f2*)icp;
            uC  = *(const f2*)up;
            icp += N_; up += N_;
        }
    }

    if (tid == 0) nsp[0] = (float)cnt;
}

// ---------------- Kernel B: parallel replay ----------------
extern "C" __global__ void __launch_bounds__(256)
snn_replay(const float* __restrict__ w,   const float* __restrict__ mu,
           const float* __restrict__ ic,  const float* __restrict__ u_re,
           float* __restrict__ out,
           const int* __restrict__ ws_eidx, const int* __restrict__ ws_cnt,
           const float* __restrict__ ws_snap)
{
#pragma clang fp contract(off)
    const int c = blockIdx.x >> 3;                       // chunk
    const int n = ((blockIdx.x & 7) << 8) + threadIdx.x; // neuron
    const float dt = 1.0f / 4096.0f;
    const float mu1 = mu[0], mu2 = mu[1];

    float* ys  = out;
    float* yev = out + (size_t)T_ * N_ * 3 + MAXSP;
    float* et  = yev + (size_t)MAXSP * N_ * 3;

    const float* sp = ws_snap + (size_t)c * 3 * N_;
    float v  = sp[n];
    float ii = sp[N_ + n];
    float ss = sp[2 * N_ + n];
    int cnt = ws_cnt[c];

    const int t0 = c << 8;
    const float* icp = ic + (size_t)t0 * N_ + n;
    const float* up  = u_re + (size_t)t0 * N_ + n;
    float* yr = ys + ((size_t)t0 * N_ + n) * 3;

    for (int k = 0; k < CHUNK; ++k) {
        const int t = t0 + k;
        const int e = ws_eidx[t];          // uniform scalar load
        const float icv = icp[0];

        float v1 = v + dt * (mu1 * ((ii + icv) - v));
        float i1 = ii + dt * ((-mu2) * ii);
        // same bit-exact fast/slow softplus as the scan
        float spv;
        if (__ballot(v < 16.0f)) {
            spv = fmaxf(v, 0.0f) + __logf(1.0f + __expf(-fabsf(v)));
        } else {
            spv = v;
        }
        float s1 = ss + dt * spv;
        bool m = (s1 >= 0.0f);

        if (e >= 0) {                      // event step (uniform branch)
            float wv_ = w[(size_t)e * N_ + n];
            float uu  = up[0];
            if (cnt < MAXSP) {             // record pre-transition state
                float* ye = yev + ((size_t)cnt * N_ + n) * 3;
                ye[0] = v1; ye[1] = i1; ye[2] = s1;
                et[(size_t)cnt * N_ + n] = m ? 1.0f : 0.0f;
                cnt++;
            }
            v  = m ? (v1 - 1.0f) : v1;
            ii = i1 + wv_;
            ss = m ? (__logf(uu) - 0.01f) : s1;
        } else {
            v = v1; ii = i1; ss = s1;
        }

        yr[0] = v; yr[1] = ii; yr[2] = ss;

        icp += N_; up += N_; yr += (size_t)3 * N_;
    }
}

extern "C" void kernel_launch(void* const* d_in, const int* in_sizes, int n_in,
                              void* d_out, int out_size, void* d_ws, size_t ws_size,
                              hipStream_t stream) {
    const float* w      = (const float*)d_in[0];
    const float* mu     = (const float*)d_in[1];
    const float* v0     = (const float*)d_in[2];
    const float* i0     = (const float*)d_in[3];
    const float* ic     = (const float*)d_in[4];
    const float* u_init = (const float*)d_in[5];
    const float* u_re   = (const float*)d_in[6];
    float* out = (float*)d_out;

    char* ws = (char*)d_ws;
    int*   ws_eidx = (int*)(ws + WS_EIDX_OFF);
    int*   ws_cnt  = (int*)(ws + WS_CNT_OFF);
    float* ws_snap = (float*)(ws + WS_SNAP_OFF);

    const size_t tail = (size_t)MAXSP + (size_t)MAXSP * N_ * 3 + (size_t)MAXSP * N_;
    int blocks = (int)((tail + 255) / 256);
    snn_init_tail<<<blocks, 256, 0, stream>>>(out);

    snn_scan<<<1, 1024, 0, stream>>>(w, mu, v0, i0, ic, u_init, u_re,
                                     out, ws_eidx, ws_cnt, ws_snap);

    snn_replay<<<NCHUNK * 8, 256, 0, stream>>>(w, mu, ic, u_re, out,
                                               ws_eidx, ws_cnt, ws_snap);
}